// Round 5
// baseline (135.446 us; speedup 1.0000x reference)
//
#include <hip/hip_runtime.h>

// Q=32, S=25, L=64, F=256, H=64
// out[q,s,i,f] = sum_j softmax_j( sum_h tanh(Wq[q,i,h]*Wh[s,j,h]) ) * hs[s,j,f]
// Wq = (qs @ W^T + b) * 2*log2(e)  (pre-scaled: exp2 arg ready), Wh = hs @ W^T + b
// tanh(x) = 1 - 2/(1+exp2(2log2e*x)); per-row constant 64 drops under softmax.
// 4 h-terms share one v_rcp (exp2 arg clamped to [-30,30]: d in [2^-30,2^30]).
// r11: r6-r10 all neutral (47-50us, VALUBusy stuck 63%) -> every version kept
// 20 trans ops/16 terms; trans (quarter-rate-or-slower wave64) dominates the
// issue budget, so VALU-side packing was invisible. This round: SOFTWARE exp2
// on the FMA pipe (magic-number range reduction + deg-4 poly + lshl_add bit
// scale, all v_pk_*_f32), trans 20 -> 4 per 16 terms. Poly rel err 4.2e-5 ->
// tanh err <= 2.1e-5 (negligible vs bf16 PV).
// total - attn - prep ~= 63-70us is FIXED harness overhead; optimize attn only.

#define NQ 32
#define NS 25
#define NL 64
#define NF 256
#define NH 64

#define K2LOG2E 2.8853900817779268f

typedef __attribute__((ext_vector_type(8))) short bf16x8;
typedef __attribute__((ext_vector_type(4))) float f32x4;
typedef __attribute__((ext_vector_type(2))) float v2f;

__device__ inline unsigned short f2bf(float x) {  // RNE
    union { float f; unsigned int u; } v; v.f = x;
    unsigned int r = v.u + 0x7fffu + ((v.u >> 16) & 1u);
    return (unsigned short)(r >> 16);
}

__device__ inline void cvt_hilo(float4 a, float4 b, bf16x8* hi, bf16x8* lo) {
    float x[8] = {a.x, a.y, a.z, a.w, b.x, b.y, b.z, b.w};
    bf16x8 h8, l8;
#pragma unroll
    for (int i = 0; i < 8; ++i) {
        union { float f; unsigned int u; } v; v.f = x[i];
        unsigned short hh = (unsigned short)(v.u >> 16);
        h8[i] = (short)hh;
        union { unsigned int u; float f; } hf; hf.u = (unsigned int)hh << 16;
        union { float f; unsigned int u; } rv; rv.f = x[i] - hf.f;
        l8[i] = (short)(unsigned short)(rv.u >> 16);
    }
    *hi = h8; *lo = l8;
}

// ---------------- prep kernel (unchanged: ~3-7us, not the bottleneck) ----
#define PROJ_BLOCKS 114
__global__ __launch_bounds__(256) void prep_kernel(
    const float* __restrict__ qs, const float* __restrict__ hs,
    const float* __restrict__ W, const float* __restrict__ b,
    float* __restrict__ Wqs, float* __restrict__ Whs,
    unsigned short* __restrict__ hsT)
{
    __shared__ unsigned short T[64 * 72];
    const int t = threadIdx.x;
    const int bid = blockIdx.x;

    if (bid < PROJ_BLOCKS) {
        const int w = t >> 6, lane = t & 63;
        const int m15 = lane & 15, quad = lane >> 4;
        const int r0 = bid * 32 + (w & 1) * 16;
        const int h0 = (w >> 1) * 32;
        const bool is_q = (r0 < 2048);
        const float* Xrow = is_q ? (qs + (size_t)(r0 + m15) * NF)
                                 : (hs + (size_t)(r0 - 2048 + m15) * NF);
        f32x4 acc[2] = {(f32x4){0.f,0.f,0.f,0.f}, (f32x4){0.f,0.f,0.f,0.f}};

#pragma unroll 2
        for (int kk = 0; kk < 8; ++kk) {
            const int f0 = kk * 32 + quad * 8;
            bf16x8 xhi, xlo;
            cvt_hilo(*(const float4*)(Xrow + f0), *(const float4*)(Xrow + f0 + 4),
                     &xhi, &xlo);
#pragma unroll
            for (int nt = 0; nt < 2; ++nt) {
                const float* Wrow = W + (size_t)(h0 + nt * 16 + m15) * NF + f0;
                bf16x8 whi, wlo;
                cvt_hilo(*(const float4*)(Wrow), *(const float4*)(Wrow + 4),
                         &whi, &wlo);
                acc[nt] = __builtin_amdgcn_mfma_f32_16x16x32_bf16(xhi, whi, acc[nt], 0, 0, 0);
                acc[nt] = __builtin_amdgcn_mfma_f32_16x16x32_bf16(xhi, wlo, acc[nt], 0, 0, 0);
                acc[nt] = __builtin_amdgcn_mfma_f32_16x16x32_bf16(xlo, whi, acc[nt], 0, 0, 0);
            }
        }
#pragma unroll
        for (int nt = 0; nt < 2; ++nt) {
            const int h = h0 + nt * 16 + m15;
            const float bias = b[h];
#pragma unroll
            for (int r = 0; r < 4; ++r) {
                const int row = r0 + quad * 4 + r;
                const float v = acc[nt][r] + bias;
                if (is_q) Wqs[(size_t)row * NH + h] = v * K2LOG2E;
                else      Whs[(size_t)(row - 2048) * NH + h] = v;
            }
        }
    } else {
        const int b2 = bid - PROJ_BLOCKS;
        const int s = b2 >> 2;
        const int f0 = (b2 & 3) * 64;
        const float4* h4p = (const float4*)(hs + (size_t)s * NL * NF);
#pragma unroll
        for (int u = 0; u < 4; ++u) {
            int idx = t + 256 * u;
            int j = idx >> 4, fq = idx & 15;
            float4 v = h4p[j * 64 + (f0 >> 2) + fq];
            T[(4 * fq + 0) * 72 + j] = f2bf(v.x);
            T[(4 * fq + 1) * 72 + j] = f2bf(v.y);
            T[(4 * fq + 2) * 72 + j] = f2bf(v.z);
            T[(4 * fq + 3) * 72 + j] = f2bf(v.w);
        }
        __syncthreads();
#pragma unroll
        for (int u = 0; u < 2; ++u) {
            int idx = t + 256 * u;
            int fl = idx >> 3, jg = idx & 7;
            uint4 v = *(const uint4*)&T[fl * 72 + jg * 8];
            *(uint4*)&hsT[(size_t)(s * 256 + f0 + fl) * 64 + jg * 8] = v;
        }
    }
}

// two-sided clamp to [-30,30] (lower clamp required by the bit-scale; changes
// results only where d < 2^-30 -> tanh delta ~2^-29, negligible). min(max()) ->
// v_med3_f32 per component.
__device__ inline v2f clamp2(v2f x) {
    v2f r;
    r[0] = fminf(fmaxf(x[0], -30.f), 30.f);
    r[1] = fminf(fmaxf(x[1], -30.f), 30.f);
    return r;
}

// software exp2 on the FMA pipe, packed pair. x must be in [-30.5, 30.5].
// t = x + 1.5*2^23 -> n = RNE(x) exact, bits(t) = 0x4B400000 + n.
// p = exp2(f) deg-4 Taylor on [-0.5,0.5], rel err <= 4.2e-5.
// result bits = bits(p) + (bits(t) << 23)  [0x4B400000<<23 == 0 mod 2^32].
__device__ inline v2f softexp2(v2f x) {
    const v2f M  = {12582912.f, 12582912.f};
    const v2f C4 = {0.0096181291f, 0.0096181291f};
    const v2f C3 = {0.0555041087f, 0.0555041087f};
    const v2f C2 = {0.2402265070f, 0.2402265070f};
    const v2f C1 = {0.6931471806f, 0.6931471806f};
    const v2f ONE = {1.f, 1.f};
    v2f t = x + M;
    v2f n = t - M;
    v2f f = x - n;
    v2f p = __builtin_elementwise_fma(f, C4, C3);
    p = __builtin_elementwise_fma(f, p, C2);
    p = __builtin_elementwise_fma(f, p, C1);
    p = __builtin_elementwise_fma(f, p, ONE);
    union { float f; unsigned int u; } t0, t1, p0, p1, r0, r1;
    t0.f = t[0]; t1.f = t[1]; p0.f = p[0]; p1.f = p[1];
    r0.u = (t0.u << 23) + p0.u;   // v_lshl_add_u32
    r1.u = (t1.u << 23) + p1.u;
    r0.u = r0.u; r1.u = r1.u;
    v2f r; r[0] = r0.f; r[1] = r1.f;
    return r;
}

// 16 terms (4 h x 4 cols): products+clamp, 8 packed softexp2 (zero trans),
// then the r10 packed rational combine over column pairs (4 shared rcps).
// v2f "repacking" between stages is register renaming -- zero instructions.
__device__ inline void score16(v2f alo, v2f ahi,
                               float4 b0, float4 b1, float4 b2, float4 b3,
                               v2f* sA, v2f* sB)
{
    // stage 1: products + two-sided clamp. xlN/xhN = {h0,h1}/{h2,h3} of col N.
    v2f xl0 = clamp2(alo * (v2f){b0.x, b0.y});
    v2f xh0 = clamp2(ahi * (v2f){b0.z, b0.w});
    v2f xl1 = clamp2(alo * (v2f){b1.x, b1.y});
    v2f xh1 = clamp2(ahi * (v2f){b1.z, b1.w});
    v2f xl2 = clamp2(alo * (v2f){b2.x, b2.y});
    v2f xh2 = clamp2(ahi * (v2f){b2.z, b2.w});
    v2f xl3 = clamp2(alo * (v2f){b3.x, b3.y});
    v2f xh3 = clamp2(ahi * (v2f){b3.z, b3.w});
    // stage 2: software exp2, packed {h pairs} per column -- all FMA-pipe.
    v2f el0 = softexp2(xl0);   // {e_h0, e_h1} col0
    v2f eh0 = softexp2(xh0);   // {e_h2, e_h3} col0
    v2f el1 = softexp2(xl1);
    v2f eh1 = softexp2(xh1);
    v2f el2 = softexp2(xl2);
    v2f eh2 = softexp2(xh2);
    v2f el3 = softexp2(xl3);
    v2f eh3 = softexp2(xh3);
    // stage 3: packed combine over column pairs (0,1)->sA and (2,3)->sB.
    v2f E0A = {el0[0], el1[0]}, E1A = {el0[1], el1[1]};
    v2f E2A = {eh0[0], eh1[0]}, E3A = {eh0[1], eh1[1]};
    v2f E0B = {el2[0], el3[0]}, E1B = {el2[1], el3[1]};
    v2f E2B = {eh2[0], eh3[0]}, E3B = {eh2[1], eh3[1]};
    v2f S01A = E0A + E1A, S23A = E2A + E3A;
    v2f S01B = E0B + E1B, S23B = E2B + E3B;
    v2f one = {1.f, 1.f}, two = {2.f, 2.f};
    v2f D01A = __builtin_elementwise_fma(E0A, E1A, S01A) + one;
    v2f D23A = __builtin_elementwise_fma(E2A, E3A, S23A) + one;
    v2f D01B = __builtin_elementwise_fma(E0B, E1B, S01B) + one;
    v2f D23B = __builtin_elementwise_fma(E2B, E3B, S23B) + one;
    v2f NUMA = __builtin_elementwise_fma(S01A + two, D23A, (S23A + two) * D01A);
    v2f NUMB = __builtin_elementwise_fma(S01B + two, D23B, (S23B + two) * D01B);
    v2f PA = D01A * D23A, PB = D01B * D23B;
    v2f RA = { __builtin_amdgcn_rcpf(PA[0]), __builtin_amdgcn_rcpf(PA[1]) };
    v2f RB = { __builtin_amdgcn_rcpf(PB[0]), __builtin_amdgcn_rcpf(PB[1]) };
    *sA = __builtin_elementwise_fma(NUMA, RA, *sA);
    *sB = __builtin_elementwise_fma(NUMB, RB, *sB);
}

// ---------------- fused attention kernel ----------------
// Grid 3200: (q, s, quarter). Block: 16 i-rows x 64 j. 256 threads.
// LDS: A f32 [16][68] @0 (4352B) | B f32 [64][68] @4352B (17408B) = 21760B -> 7 blk/CU
//      att bf16 [16][72] overlaps A after scores (barrier-guarded).
#define AS 68
#define B_OFF 1088          // floats (16*68)
#define SMEMF 5440          // 21760 B

__global__ __launch_bounds__(256, 7) void attn_kernel(
    const float* __restrict__ Wqs, const float* __restrict__ Whs,
    const unsigned short* __restrict__ hsT, float* __restrict__ out)
{
    __shared__ float smem[SMEMF];
    const int t = threadIdx.x;
    const int bid = blockIdx.x;
    const int qt = bid & 3;
    const int s = (bid >> 2) % NS;
    const int q = bid / (4 * NS);

    // ---- stage A (16x64) and B (64x64), row-major stride 68 ----
    {
        const float4* a4 = (const float4*)(Wqs + ((size_t)q * NL + qt * 16) * NH);
        const float4* b4 = (const float4*)(Whs + (size_t)s * NL * NH);
        {
            int i = t >> 4, g = t & 15;
            *(float4*)&smem[i * AS + 4 * g] = a4[t];
        }
#pragma unroll
        for (int u = 0; u < 4; ++u) {
            int idx = t + 256 * u;
            int j = idx >> 4, g = idx & 15;
            *(float4*)&smem[B_OFF + j * AS + 4 * g] = b4[idx];
        }
    }
    __syncthreads();

    // ---- scores: row i = t>>4, cols jn+16*jj ----
    const int irow = t >> 4;
    const int jn = t & 15;
    v2f sumA = {0.f, 0.f}, sumB = {0.f, 0.f};
    {
        const float* Ab = &smem[irow * AS];
        const float* Bb = &smem[B_OFF + jn * AS];

#pragma unroll 4
        for (int h4 = 0; h4 < 16; ++h4) {
            float4 av = *(const float4*)(Ab + 4 * h4);
            v2f alo = {av.x, av.y}, ahi = {av.z, av.w};
            float4 b0 = *(const float4*)(Bb + 4 * h4);
            float4 b1 = *(const float4*)(Bb + 16 * AS + 4 * h4);
            float4 b2 = *(const float4*)(Bb + 32 * AS + 4 * h4);
            float4 b3 = *(const float4*)(Bb + 48 * AS + 4 * h4);
            score16(alo, ahi, b0, b1, b2, b3, &sumA, &sumB);
        }
    }
    __syncthreads();  // all A/B reads complete before att overwrites A region

    // ---- in-wave softmax over j (min-form: score = -2*sum + const) ----
    {
        float sum[4] = {sumA[0], sumA[1], sumB[0], sumB[1]};  // cols jn+16*jj
        float mn = fminf(fminf(sum[0], sum[1]), fminf(sum[2], sum[3]));
        mn = fminf(mn, __shfl_xor(mn, 1));
        mn = fminf(mn, __shfl_xor(mn, 2));
        mn = fminf(mn, __shfl_xor(mn, 4));
        mn = fminf(mn, __shfl_xor(mn, 8));
        float p[4];
        float d = 0.f;
#pragma unroll
        for (int jj = 0; jj < 4; ++jj) {
            p[jj] = __builtin_amdgcn_exp2f((mn - sum[jj]) * K2LOG2E);
            d += p[jj];
        }
        d += __shfl_xor(d, 1);
        d += __shfl_xor(d, 2);
        d += __shfl_xor(d, 4);
        d += __shfl_xor(d, 8);
        const float inv = __builtin_amdgcn_rcpf(d);
        unsigned short* att = (unsigned short*)smem;  // [16][72] bf16 over dead A
#pragma unroll
        for (int jj = 0; jj < 4; ++jj)
            att[irow * 72 + jn + 16 * jj] = f2bf(p[jj] * inv);
    }
    __syncthreads();

    // ---- PV via bf16 MFMA: [16 x 64j] @ [64j x 256f]; wave wv -> f-tiles wv*4.. ----
    const int lane = t & 63;
    const int wv = t >> 6;
    const int m15 = lane & 15;
    const int quad = lane >> 4;

    bf16x8 afr[2];  // A[m=lane&15][k=quad*8+idx]
#pragma unroll
    for (int k = 0; k < 2; ++k)
        afr[k] = *(const bf16x8*)((const char*)smem + m15 * 144 + k * 64 + quad * 16);

    const unsigned short* hsTs = hsT + (size_t)s * NF * NL;
    f32x4 acc[4];
#pragma unroll
    for (int n = 0; n < 4; ++n) acc[n] = (f32x4){0.f, 0.f, 0.f, 0.f};

#pragma unroll
    for (int k = 0; k < 2; ++k) {
        bf16x8 bfr[4];  // B[k][n=lane&15]: hsT row f, 8 consecutive j
#pragma unroll
        for (int n = 0; n < 4; ++n)
            bfr[n] = *(const bf16x8*)(hsTs
                        + (size_t)((wv * 4 + n) * 16 + m15) * 64 + k * 32 + quad * 8);
#pragma unroll
        for (int n = 0; n < 4; ++n)
            acc[n] = __builtin_amdgcn_mfma_f32_16x16x32_bf16(afr[k], bfr[n], acc[n], 0, 0, 0);
    }

    // C layout: col(f) = lane&15, row(i) = quad*4 + reg
    const size_t obase = ((size_t)(q * NS + s) * NL + qt * 16) * NF;
#pragma unroll
    for (int n = 0; n < 4; ++n)
#pragma unroll
        for (int r = 0; r < 4; ++r)
            out[obase + (size_t)(quad * 4 + r) * NF + (wv * 4 + n) * 16 + m15] = acc[n][r];
}

extern "C" void kernel_launch(void* const* d_in, const int* in_sizes, int n_in,
                              void* d_out, int out_size, void* d_ws, size_t ws_size,
                              hipStream_t stream) {
    const float* qs = (const float*)d_in[0];
    const float* hs = (const float*)d_in[1];
    const float* W  = (const float*)d_in[2];
    const float* b  = (const float*)d_in[3];
    float* out = (float*)d_out;

    float* Wqs = (float*)d_ws;                         // 131072 f
    float* Whs = Wqs + NQ * NL * NH;                   // 102400 f
    unsigned short* hsT = (unsigned short*)(Whs + NS * NL * NH);  // 409600 bf16

    prep_kernel<<<PROJ_BLOCKS + NS * 4, 256, 0, stream>>>(qs, hs, W, b, Wqs, Whs, hsT);
    attn_kernel<<<NQ * NS * 4, 256, 0, stream>>>(Wqs, Whs, hsT, out);
}

// Round 6
// 119.054 us; speedup vs baseline: 1.1377x; 1.1377x over previous
//
#include <hip/hip_runtime.h>

// Q=32, S=25, L=64, F=256, H=64
// out[q,s,i,f] = sum_j softmax_j( sum_h tanh(Wq[q,i,h]*Wh[s,j,h]) ) * hs[s,j,f]
// Wq = (qs @ W^T + b) * 2*log2(e)  (pre-scaled: exp2 arg ready), Wh = hs @ W^T + b
// tanh(x) = 1 - 2/(1+exp2(2log2e*x)); per-row constant 64 drops under softmax.
// 4 h-terms share one v_rcp (exp2 arg clamped <= 30: d<=2^61, den<=2^122, safe).
// r12: r11 softexp2 REVERTED (trans->FMA trade regressed 43%: time tracks VALU
// count). r6-r11 jointly show duration ~= SUM of pipe demands (LDS 20us + VALU
// 15us + trans 11us ~= 46us measured): zero cross-pipe overlap. Cause: 7
// waves/SIMD from 7 barrier-aligned blocks run the IDENTICAL loop phase-locked
// (convoys: all burst ds_reads together -> all stall; all burst exp2 together
// -> trans contention while main idles). Fix: stagger each wave's h4 start by
// (bid + wave_id) & 15 -- same-SIMD waves land in different phases, pipes
// interleave. Only change vs r10; FP reassociation only.
// total - attn - prep ~= 63-70us is FIXED harness overhead; optimize attn only.

#define NQ 32
#define NS 25
#define NL 64
#define NF 256
#define NH 64

#define K2LOG2E 2.8853900817779268f

typedef __attribute__((ext_vector_type(8))) short bf16x8;
typedef __attribute__((ext_vector_type(4))) float f32x4;
typedef __attribute__((ext_vector_type(2))) float v2f;

__device__ inline unsigned short f2bf(float x) {  // RNE
    union { float f; unsigned int u; } v; v.f = x;
    unsigned int r = v.u + 0x7fffu + ((v.u >> 16) & 1u);
    return (unsigned short)(r >> 16);
}

__device__ inline void cvt_hilo(float4 a, float4 b, bf16x8* hi, bf16x8* lo) {
    float x[8] = {a.x, a.y, a.z, a.w, b.x, b.y, b.z, b.w};
    bf16x8 h8, l8;
#pragma unroll
    for (int i = 0; i < 8; ++i) {
        union { float f; unsigned int u; } v; v.f = x[i];
        unsigned short hh = (unsigned short)(v.u >> 16);
        h8[i] = (short)hh;
        union { unsigned int u; float f; } hf; hf.u = (unsigned int)hh << 16;
        union { float f; unsigned int u; } rv; rv.f = x[i] - hf.f;
        l8[i] = (short)(unsigned short)(rv.u >> 16);
    }
    *hi = h8; *lo = l8;
}

// ---------------- prep kernel (unchanged: ~3-7us, not the bottleneck) ----
#define PROJ_BLOCKS 114
__global__ __launch_bounds__(256) void prep_kernel(
    const float* __restrict__ qs, const float* __restrict__ hs,
    const float* __restrict__ W, const float* __restrict__ b,
    float* __restrict__ Wqs, float* __restrict__ Whs,
    unsigned short* __restrict__ hsT)
{
    __shared__ unsigned short T[64 * 72];
    const int t = threadIdx.x;
    const int bid = blockIdx.x;

    if (bid < PROJ_BLOCKS) {
        const int w = t >> 6, lane = t & 63;
        const int m15 = lane & 15, quad = lane >> 4;
        const int r0 = bid * 32 + (w & 1) * 16;
        const int h0 = (w >> 1) * 32;
        const bool is_q = (r0 < 2048);
        const float* Xrow = is_q ? (qs + (size_t)(r0 + m15) * NF)
                                 : (hs + (size_t)(r0 - 2048 + m15) * NF);
        f32x4 acc[2] = {(f32x4){0.f,0.f,0.f,0.f}, (f32x4){0.f,0.f,0.f,0.f}};

#pragma unroll 2
        for (int kk = 0; kk < 8; ++kk) {
            const int f0 = kk * 32 + quad * 8;
            bf16x8 xhi, xlo;
            cvt_hilo(*(const float4*)(Xrow + f0), *(const float4*)(Xrow + f0 + 4),
                     &xhi, &xlo);
#pragma unroll
            for (int nt = 0; nt < 2; ++nt) {
                const float* Wrow = W + (size_t)(h0 + nt * 16 + m15) * NF + f0;
                bf16x8 whi, wlo;
                cvt_hilo(*(const float4*)(Wrow), *(const float4*)(Wrow + 4),
                         &whi, &wlo);
                acc[nt] = __builtin_amdgcn_mfma_f32_16x16x32_bf16(xhi, whi, acc[nt], 0, 0, 0);
                acc[nt] = __builtin_amdgcn_mfma_f32_16x16x32_bf16(xhi, wlo, acc[nt], 0, 0, 0);
                acc[nt] = __builtin_amdgcn_mfma_f32_16x16x32_bf16(xlo, whi, acc[nt], 0, 0, 0);
            }
        }
#pragma unroll
        for (int nt = 0; nt < 2; ++nt) {
            const int h = h0 + nt * 16 + m15;
            const float bias = b[h];
#pragma unroll
            for (int r = 0; r < 4; ++r) {
                const int row = r0 + quad * 4 + r;
                const float v = acc[nt][r] + bias;
                if (is_q) Wqs[(size_t)row * NH + h] = v * K2LOG2E;
                else      Whs[(size_t)(row - 2048) * NH + h] = v;
            }
        }
    } else {
        const int b2 = bid - PROJ_BLOCKS;
        const int s = b2 >> 2;
        const int f0 = (b2 & 3) * 64;
        const float4* h4p = (const float4*)(hs + (size_t)s * NL * NF);
#pragma unroll
        for (int u = 0; u < 4; ++u) {
            int idx = t + 256 * u;
            int j = idx >> 4, fq = idx & 15;
            float4 v = h4p[j * 64 + (f0 >> 2) + fq];
            T[(4 * fq + 0) * 72 + j] = f2bf(v.x);
            T[(4 * fq + 1) * 72 + j] = f2bf(v.y);
            T[(4 * fq + 2) * 72 + j] = f2bf(v.z);
            T[(4 * fq + 3) * 72 + j] = f2bf(v.w);
        }
        __syncthreads();
#pragma unroll
        for (int u = 0; u < 2; ++u) {
            int idx = t + 256 * u;
            int fl = idx >> 3, jg = idx & 7;
            uint4 v = *(const uint4*)&T[fl * 72 + jg * 8];
            *(uint4*)&hsT[(size_t)(s * 256 + f0 + fl) * 64 + jg * 8] = v;
        }
    }
}

// 16 terms (4 h x 4 cols), r10 form: stage1 pk mul/min, stage2 16 hw exp2,
// stage3 packed rational combine over column pairs, 4 shared rcps.
__device__ inline void score16(v2f alo, v2f ahi,
                               float4 b0, float4 b1, float4 b2, float4 b3,
                               v2f* sA, v2f* sB)
{
    const v2f vcl = {30.f, 30.f};
    v2f xl0 = __builtin_elementwise_min(alo * (v2f){b0.x, b0.y}, vcl);
    v2f xh0 = __builtin_elementwise_min(ahi * (v2f){b0.z, b0.w}, vcl);
    v2f xl1 = __builtin_elementwise_min(alo * (v2f){b1.x, b1.y}, vcl);
    v2f xh1 = __builtin_elementwise_min(ahi * (v2f){b1.z, b1.w}, vcl);
    v2f xl2 = __builtin_elementwise_min(alo * (v2f){b2.x, b2.y}, vcl);
    v2f xh2 = __builtin_elementwise_min(ahi * (v2f){b2.z, b2.w}, vcl);
    v2f xl3 = __builtin_elementwise_min(alo * (v2f){b3.x, b3.y}, vcl);
    v2f xh3 = __builtin_elementwise_min(ahi * (v2f){b3.z, b3.w}, vcl);
    float e00 = __builtin_amdgcn_exp2f(xl0[0]);
    float e10 = __builtin_amdgcn_exp2f(xl0[1]);
    float e20 = __builtin_amdgcn_exp2f(xh0[0]);
    float e30 = __builtin_amdgcn_exp2f(xh0[1]);
    float e01 = __builtin_amdgcn_exp2f(xl1[0]);
    float e11 = __builtin_amdgcn_exp2f(xl1[1]);
    float e21 = __builtin_amdgcn_exp2f(xh1[0]);
    float e31 = __builtin_amdgcn_exp2f(xh1[1]);
    float e02 = __builtin_amdgcn_exp2f(xl2[0]);
    float e12 = __builtin_amdgcn_exp2f(xl2[1]);
    float e22 = __builtin_amdgcn_exp2f(xh2[0]);
    float e32 = __builtin_amdgcn_exp2f(xh2[1]);
    float e03 = __builtin_amdgcn_exp2f(xl3[0]);
    float e13 = __builtin_amdgcn_exp2f(xl3[1]);
    float e23 = __builtin_amdgcn_exp2f(xh3[0]);
    float e33 = __builtin_amdgcn_exp2f(xh3[1]);
    v2f E0A = {e00, e01}, E1A = {e10, e11}, E2A = {e20, e21}, E3A = {e30, e31};
    v2f E0B = {e02, e03}, E1B = {e12, e13}, E2B = {e22, e23}, E3B = {e32, e33};
    v2f S01A = E0A + E1A, S23A = E2A + E3A;
    v2f S01B = E0B + E1B, S23B = E2B + E3B;
    v2f one = {1.f, 1.f}, two = {2.f, 2.f};
    v2f D01A = __builtin_elementwise_fma(E0A, E1A, S01A) + one;
    v2f D23A = __builtin_elementwise_fma(E2A, E3A, S23A) + one;
    v2f D01B = __builtin_elementwise_fma(E0B, E1B, S01B) + one;
    v2f D23B = __builtin_elementwise_fma(E2B, E3B, S23B) + one;
    v2f NUMA = __builtin_elementwise_fma(S01A + two, D23A, (S23A + two) * D01A);
    v2f NUMB = __builtin_elementwise_fma(S01B + two, D23B, (S23B + two) * D01B);
    v2f PA = D01A * D23A, PB = D01B * D23B;
    v2f RA = { __builtin_amdgcn_rcpf(PA[0]), __builtin_amdgcn_rcpf(PA[1]) };
    v2f RB = { __builtin_amdgcn_rcpf(PB[0]), __builtin_amdgcn_rcpf(PB[1]) };
    *sA = __builtin_elementwise_fma(NUMA, RA, *sA);
    *sB = __builtin_elementwise_fma(NUMB, RB, *sB);
}

// ---------------- fused attention kernel ----------------
// Grid 3200: (q, s, quarter). Block: 16 i-rows x 64 j. 256 threads.
// LDS: A f32 [16][68] @0 (4352B) | B f32 [64][68] @4352B (17408B) = 21760B -> 7 blk/CU
//      att bf16 [16][72] overlaps A after scores (barrier-guarded).
#define AS 68
#define B_OFF 1088          // floats (16*68)
#define SMEMF 5440          // 21760 B

__global__ __launch_bounds__(256, 7) void attn_kernel(
    const float* __restrict__ Wqs, const float* __restrict__ Whs,
    const unsigned short* __restrict__ hsT, float* __restrict__ out)
{
    __shared__ float smem[SMEMF];
    const int t = threadIdx.x;
    const int bid = blockIdx.x;
    const int qt = bid & 3;
    const int s = (bid >> 2) % NS;
    const int q = bid / (4 * NS);

    // ---- stage A (16x64) and B (64x64), row-major stride 68 ----
    {
        const float4* a4 = (const float4*)(Wqs + ((size_t)q * NL + qt * 16) * NH);
        const float4* b4 = (const float4*)(Whs + (size_t)s * NL * NH);
        {
            int i = t >> 4, g = t & 15;
            *(float4*)&smem[i * AS + 4 * g] = a4[t];
        }
#pragma unroll
        for (int u = 0; u < 4; ++u) {
            int idx = t + 256 * u;
            int j = idx >> 4, g = idx & 15;
            *(float4*)&smem[B_OFF + j * AS + 4 * g] = b4[idx];
        }
    }
    __syncthreads();

    // ---- scores: row i = t>>4, cols jn+16*jj ----
    // Convoy-breaking stagger: each wave starts its h4 loop at a different
    // phase (bid decorrelates same-SIMD waves of different blocks, wv the
    // SIMDs within a block). Pipes (LDS/trans/main-VALU) then interleave
    // across waves instead of bursting in lockstep.
    const int irow = t >> 4;
    const int jn = t & 15;
    const int s0h = (bid + (t >> 6)) & 15;
    v2f sumA = {0.f, 0.f}, sumB = {0.f, 0.f};
    {
        const float* Ab = &smem[irow * AS];
        const float* Bb = &smem[B_OFF + jn * AS];

#pragma unroll 4
        for (int it = 0; it < 16; ++it) {
            const int h4 = (it + s0h) & 15;
            float4 av = *(const float4*)(Ab + 4 * h4);
            v2f alo = {av.x, av.y}, ahi = {av.z, av.w};
            float4 b0 = *(const float4*)(Bb + 4 * h4);
            float4 b1 = *(const float4*)(Bb + 16 * AS + 4 * h4);
            float4 b2 = *(const float4*)(Bb + 32 * AS + 4 * h4);
            float4 b3 = *(const float4*)(Bb + 48 * AS + 4 * h4);
            score16(alo, ahi, b0, b1, b2, b3, &sumA, &sumB);
        }
    }
    __syncthreads();  // all A/B reads complete before att overwrites A region

    // ---- in-wave softmax over j (min-form: score = -2*sum + const) ----
    {
        float sum[4] = {sumA[0], sumA[1], sumB[0], sumB[1]};  // cols jn+16*jj
        float mn = fminf(fminf(sum[0], sum[1]), fminf(sum[2], sum[3]));
        mn = fminf(mn, __shfl_xor(mn, 1));
        mn = fminf(mn, __shfl_xor(mn, 2));
        mn = fminf(mn, __shfl_xor(mn, 4));
        mn = fminf(mn, __shfl_xor(mn, 8));
        float p[4];
        float d = 0.f;
#pragma unroll
        for (int jj = 0; jj < 4; ++jj) {
            p[jj] = __builtin_amdgcn_exp2f((mn - sum[jj]) * K2LOG2E);
            d += p[jj];
        }
        d += __shfl_xor(d, 1);
        d += __shfl_xor(d, 2);
        d += __shfl_xor(d, 4);
        d += __shfl_xor(d, 8);
        const float inv = __builtin_amdgcn_rcpf(d);
        unsigned short* att = (unsigned short*)smem;  // [16][72] bf16 over dead A
#pragma unroll
        for (int jj = 0; jj < 4; ++jj)
            att[irow * 72 + jn + 16 * jj] = f2bf(p[jj] * inv);
    }
    __syncthreads();

    // ---- PV via bf16 MFMA: [16 x 64j] @ [64j x 256f]; wave wv -> f-tiles wv*4.. ----
    const int lane = t & 63;
    const int wv = t >> 6;
    const int m15 = lane & 15;
    const int quad = lane >> 4;

    bf16x8 afr[2];  // A[m=lane&15][k=quad*8+idx]
#pragma unroll
    for (int k = 0; k < 2; ++k)
        afr[k] = *(const bf16x8*)((const char*)smem + m15 * 144 + k * 64 + quad * 16);

    const unsigned short* hsTs = hsT + (size_t)s * NF * NL;
    f32x4 acc[4];
#pragma unroll
    for (int n = 0; n < 4; ++n) acc[n] = (f32x4){0.f, 0.f, 0.f, 0.f};

#pragma unroll
    for (int k = 0; k < 2; ++k) {
        bf16x8 bfr[4];  // B[k][n=lane&15]: hsT row f, 8 consecutive j
#pragma unroll
        for (int n = 0; n < 4; ++n)
            bfr[n] = *(const bf16x8*)(hsTs
                        + (size_t)((wv * 4 + n) * 16 + m15) * 64 + k * 32 + quad * 8);
#pragma unroll
        for (int n = 0; n < 4; ++n)
            acc[n] = __builtin_amdgcn_mfma_f32_16x16x32_bf16(afr[k], bfr[n], acc[n], 0, 0, 0);
    }

    // C layout: col(f) = lane&15, row(i) = quad*4 + reg
    const size_t obase = ((size_t)(q * NS + s) * NL + qt * 16) * NF;
#pragma unroll
    for (int n = 0; n < 4; ++n)
#pragma unroll
        for (int r = 0; r < 4; ++r)
            out[obase + (size_t)(quad * 4 + r) * NF + (wv * 4 + n) * 16 + m15] = acc[n][r];
}

extern "C" void kernel_launch(void* const* d_in, const int* in_sizes, int n_in,
                              void* d_out, int out_size, void* d_ws, size_t ws_size,
                              hipStream_t stream) {
    const float* qs = (const float*)d_in[0];
    const float* hs = (const float*)d_in[1];
    const float* W  = (const float*)d_in[2];
    const float* b  = (const float*)d_in[3];
    float* out = (float*)d_out;

    float* Wqs = (float*)d_ws;                         // 131072 f
    float* Whs = Wqs + NQ * NL * NH;                   // 102400 f
    unsigned short* hsT = (unsigned short*)(Whs + NS * NL * NH);  // 409600 bf16

    prep_kernel<<<PROJ_BLOCKS + NS * 4, 256, 0, stream>>>(qs, hs, W, b, Wqs, Whs, hsT);
    attn_kernel<<<NQ * NS * 4, 256, 0, stream>>>(Wqs, Whs, hsT, out);
}